// Round 9
// baseline (43.322 us; speedup 1.0000x reference)
//
#include <hip/hip_runtime.h>
#include <math.h>

#define B_ 16
#define T_ 2048
#define N_ 8
#define D_ 512
#define DTW 4           // d-tiles (of 16) per wave
#define BG 4            // batches per main block

// -2*pi/2048
#define NEG_W0 (-3.0679615757712823e-3f)
// -2*pi/32
#define NEG_W32 (-0.19634954084936207f)
// -2*pi/1024
#define NEG_W1024 (-6.1359231515425647e-3f)
// -2*ln(10000)/512
#define NEG_LDIV (-0.035977892078031555f)

typedef __attribute__((ext_vector_type(8))) short bf16x8;
typedef __attribute__((ext_vector_type(4))) float f32x4;

// fp32 -> bf16 (round-to-nearest-even)
static __device__ __forceinline__ short f2bf(float f) {
  unsigned int u = __float_as_uint(f);
  unsigned int r = u + 0x7FFFu + ((u >> 16) & 1u);
  return (short)(r >> 16);
}

// ---- launch 1: blocks <256 do the folded radix-32 FFT (unchanged math);
//      blocks >=256 build FET[2048][512]: row t = fixed-embedding row t
//      (d even: sin(t*div_{d/2}), d odd: cos). Independent work, one launch.
__global__ __launch_bounds__(1024) void fft_tab_kernel(
    const float* __restrict__ x, float* __restrict__ pmax,
    float* __restrict__ nyqS, float* __restrict__ tab) {
  __shared__ __align__(16) float2 ybuf[1024];
  __shared__ __align__(16) float2 Bl[1024];
  __shared__ __align__(16) float2 part[1024];
  __shared__ float swav[16];
  __shared__ float pwav[8];
  int tid = threadIdx.x;
  int blk = blockIdx.x;

  if (blk >= 256) {                       // ---- table generator ----
    if (tab) {
      int idx = (blk - 256) * 1024 + tid; // one float4 per thread
      int t = idx >> 7;
      int d4 = idx & 127;
      float ft = (float)t;
      float dv0 = expf((float)(d4 * 2) * NEG_LDIV);
      float dv1 = expf((float)(d4 * 2 + 1) * NEG_LDIV);
      f32x4 v;
      float s0, c0, s1, c1;
      sincosf(ft * dv0, &s0, &c0);
      sincosf(ft * dv1, &s1, &c1);
      v[0] = s0; v[1] = c0; v[2] = s1; v[3] = c1;
      *(f32x4*)(tab + (size_t)idx * 4) = v;
    }
    return;
  }

  int bn = blk >> 1, parity = blk & 1;
  int b = bn >> 3, n = bn & 7;
  const float* xb = x + (size_t)b * (T_ * N_) + n;

  float va = xb[tid * 8];
  float vb = xb[(tid + 1024) * 8];
  float ea = va + vb;
  float sgn = (tid & 1) ? -ea : ea;       // Nyquist partial (-1)^t e_t
#pragma unroll
  for (int off = 32; off > 0; off >>= 1) sgn += __shfl_down(sgn, off);
  if ((tid & 63) == 0) swav[tid >> 6] = sgn;

  if (parity == 0) {
    ((float*)ybuf)[tid] = ea;
  } else {
    float o = va - vb;
    float c0, s0;
    sincosf((float)tid * NEG_W0, &s0, &c0);
    ybuf[tid] = make_float2(o * c0, o * s0);
  }
  __syncthreads();

  int m0 = tid & 31, t0 = tid >> 5;
  float d1 = (float)m0 * NEG_W32;
  float K1 = 2.0f * cosf(d1);
  float c = 1.f, s = 0.f, cp, sp;
  sincosf(-d1, &sp, &cp);
  float ar = 0.f, ai = 0.f;
  if (parity == 0) {
    const float* ya = (const float*)ybuf;
#pragma unroll 8
    for (int t1 = 0; t1 < 32; ++t1) {
      float y = ya[t1 * 32 + t0];
      ar = fmaf(y, c, ar); ai = fmaf(y, s, ai);
      float nc = fmaf(K1, c, -cp), ns = fmaf(K1, s, -sp);
      cp = c; sp = s; c = nc; s = ns;
    }
  } else {
#pragma unroll 8
    for (int t1 = 0; t1 < 32; ++t1) {
      float2 y = ybuf[t1 * 32 + t0];
      ar = fmaf(y.x, c, fmaf(-y.y, s, ar));
      ai = fmaf(y.x, s, fmaf(y.y, c, ai));
      float nc = fmaf(K1, c, -cp), ns = fmaf(K1, s, -sp);
      cp = c; sp = s; c = nc; s = ns;
    }
  }
  {
    float ct, st;
    sincosf((float)(t0 * m0) * NEG_W1024, &st, &ct);
    Bl[t0 * 32 + m0] = make_float2(ar * ct - ai * st, fmaf(ar, st, ai * ct));
  }
  __syncthreads();

  int m02 = tid & 31;
  int m1 = (tid >> 5) & 15;
  int h = tid >> 9;
  float d2 = (float)m1 * NEG_W32;
  float K2 = 2.0f * cosf(d2);
  int t0s = h * 16;
  float c2, s2, c2p, s2p;
  sincosf((float)t0s * d2, &s2, &c2);
  sincosf((float)(t0s - 1) * d2, &s2p, &c2p);
  float yr = 0.f, yi = 0.f;
#pragma unroll 8
  for (int j = 0; j < 16; ++j) {
    float2 bv = Bl[(t0s + j) * 32 + m02];
    yr = fmaf(bv.x, c2, fmaf(-bv.y, s2, yr));
    yi = fmaf(bv.x, s2, fmaf(bv.y, c2, yi));
    float nc = fmaf(K2, c2, -c2p), ns = fmaf(K2, s2, -s2p);
    c2p = c2; s2p = s2; c2 = nc; s2 = ns;
  }
  part[tid] = make_float2(yr, yi);
  __syncthreads();
  if (tid < 512) {
    float2 pa = part[tid], pb = part[tid + 512];
    float rr = pa.x + pb.x, ii = pa.y + pb.y;
    float P = fmaf(rr, rr, ii * ii);
#pragma unroll
    for (int off = 32; off > 0; off >>= 1) P = fmaxf(P, __shfl_down(P, off));
    if ((tid & 63) == 0) pwav[tid >> 6] = P;
  }
  __syncthreads();
  if (tid < 64) {
    float mxv = (tid < 8) ? pwav[tid] : 0.f;
    float svv = (tid < 16) ? swav[tid] : 0.f;
#pragma unroll
    for (int off = 8; off > 0; off >>= 1) {
      mxv = fmaxf(mxv, __shfl_down(mxv, off));
      svv += __shfl_down(svv, off);
    }
    if (tid == 0) {
      pmax[blk] = mxv;                    // unconditional plain store
      if (parity == 0) nyqS[bn] = svv;
    }
  }
}

// ---- main: MFMA conv+temporal (k-slots 0..23 conv, 24..31 rank-7 temporal
// outer product), cyc from precomputed FET table, 4 batches per block.
// C^T layout (verified R8): lane c = t-col, rows = 4 consecutive d -> one
// 16B store/lane. Blocks: blk&127 = t-tile (16 rows), blk>>7 = batch group.
__global__ __launch_bounds__(512, 4) void main_kernel(
    const float* __restrict__ x, const int* __restrict__ xmark,
    const float* __restrict__ convw, const float* __restrict__ pmax,
    const float* __restrict__ nyqS, const float* __restrict__ tab,
    float* __restrict__ out) {
  int tid = threadIdx.x;
  int lane = tid & 63;
  int w = tid >> 6;            // wave 0..7 -> d in [w*64, w*64+64)
  int c = lane & 15;           // B t-col / C t-col / A d-row
  int g = lane >> 4;           // k-slot group / C d-subgroup
  int blk = blockIdx.x;
  int bg = blk >> 7;           // batch group: b = bg*BG + j
  int t0 = (blk & 127) * 16;   // same-ttile blocks are 128 apart -> same XCD

  // w1/w0 for the BG batches (Nyquist-argmax channel counts)
  float w1v[BG], w0v[BG];
#pragma unroll
  for (int j = 0; j < BG; ++j) {
    int b = bg * BG + j;
    int m = 0;
#pragma unroll
    for (int nn = 0; nn < 8; ++nn) {
      int bn = b * 8 + nn;
      float mx = fmaxf(pmax[2 * bn], pmax[2 * bn + 1]);
      float S = nyqS[bn];
      if (S * S > mx) ++m;
    }
    w1v[j] = (float)(8 - m) * 0.125f;
    w0v[j] = (float)m * 0.125f;
  }

  // A-frags: conv weights (g<3: A[d][g*8+n] = W[d][n][g]) / temporal rows
  // (g==3: A[d][24+p] = tab_p[d] = FET[p][d], p<7; slot 31 = 0)
  bf16x8 afrag[DTW];
#pragma unroll
  for (int q = 0; q < DTW; ++q) {
    int dt = w * DTW + q;
    int d = dt * 16 + c;
    if (g < 3) {
      const float* wb = convw + d * 24 + g;
#pragma unroll
      for (int j = 0; j < 8; ++j) afrag[q][j] = f2bf(wb[j * 3]);
    } else {
      float divv = expf((float)(d >> 1) * NEG_LDIV);
      float s1, c1;
      sincosf(divv, &s1, &c1);
      int odd = d & 1;
      afrag[q][0] = f2bf(odd ? 1.f : 0.f);
      float ps = s1, pc = c1;
      afrag[q][1] = f2bf(odd ? pc : ps);
#pragma unroll
      for (int p = 2; p < 7; ++p) {
        float ns = fmaf(ps, c1, pc * s1);
        float nc = fmaf(pc, c1, -ps * s1);
        ps = ns; pc = nc;
        afrag[q][p] = f2bf(odd ? pc : ps);
      }
      afrag[q][7] = 0;
    }
  }

  // FET row slices for the cyc epilogue: fet[q] = FET[t0+c][dt*16+g*4 ..+4)
  f32x4 fet[DTW];
  if (tab) {
#pragma unroll
    for (int q = 0; q < DTW; ++q) {
      int dt = w * DTW + q;
      fet[q] = *(const f32x4*)(tab + (size_t)(t0 + c) * D_ + dt * 16 + g * 4);
    }
  } else {                     // fallback: compute (8 sincosf)
    float tl = (float)(t0 + c);
#pragma unroll
    for (int q = 0; q < DTW; ++q) {
      int i0 = ((w * DTW + q) * 16 + g * 4) >> 1;
      float dv0 = expf((float)i0 * NEG_LDIV);
      float dv1 = expf((float)(i0 + 1) * NEG_LDIV);
      float s0, c0, s1, c1;
      sincosf(tl * dv0, &s0, &c0);
      sincosf(tl * dv1, &s1, &c1);
      fet[q][0] = s0; fet[q][1] = c0; fet[q][2] = s1; fet[q][3] = c1;
    }
  }

  const f32x4 zac = {0.f, 0.f, 0.f, 0.f};
#pragma unroll
  for (int j = 0; j < BG; ++j) {
    int b = bg * BG + j;
    // B-frag: x-window rows (g<3) / mark counts (g==3)
    bf16x8 bfrag;
    if (g < 3) {
      int row = (t0 + c + g - 1) & (T_ - 1);    // circular pad
      const float4* xr = (const float4*)(x + ((size_t)b * T_ + row) * N_);
      float4 lo = xr[0], hi = xr[1];
      bfrag[0] = f2bf(lo.x); bfrag[1] = f2bf(lo.y);
      bfrag[2] = f2bf(lo.z); bfrag[3] = f2bf(lo.w);
      bfrag[4] = f2bf(hi.x); bfrag[5] = f2bf(hi.y);
      bfrag[6] = f2bf(hi.z); bfrag[7] = f2bf(hi.w);
    } else {
      int4 mk = *(const int4*)(xmark + ((size_t)b * T_ + t0 + c) * 4);
#pragma unroll
      for (int p = 0; p < 8; ++p) {
        int cv = (mk.x == p) + (mk.y == p) + (mk.z == p) + (mk.w == p);
        bfrag[p] = f2bf((float)cv);
      }
    }
    float w1 = w1v[j], w0 = w0v[j];
#pragma unroll
    for (int q = 0; q < DTW; ++q) {
      f32x4 acc = __builtin_amdgcn_mfma_f32_16x16x32_bf16(
          afrag[q], bfrag, zac, 0, 0, 0);
      f32x4 ov;
      ov[0] = fmaf(w1, fet[q][0], acc[0]);
      ov[1] = fmaf(w1, fet[q][1], acc[1]) + w0;
      ov[2] = fmaf(w1, fet[q][2], acc[2]);
      ov[3] = fmaf(w1, fet[q][3], acc[3]) + w0;
      int dt = w * DTW + q;
      __builtin_nontemporal_store(
          ov, (f32x4*)(out + ((size_t)b * T_ + t0 + c) * D_ + dt * 16 + g * 4));
    }
  }
}

extern "C" void kernel_launch(void* const* d_in, const int* in_sizes, int n_in,
                              void* d_out, int out_size, void* d_ws, size_t ws_size,
                              hipStream_t stream) {
  const float* x = (const float*)d_in[0];
  const int* xmark = (const int*)d_in[1];
  const float* convw = (const float*)d_in[2];
  float* out = (float*)d_out;

  float* pmax = (float*)d_ws;                  // 256 floats
  float* nyqS = pmax + 256;                    // 128 floats
  size_t need = 4096 + (size_t)T_ * D_ * 4;    // slots + 4 MB FET
  float* tab = (ws_size >= need) ? (float*)((char*)d_ws + 4096) : nullptr;

  fft_tab_kernel<<<512, 1024, 0, stream>>>(x, pmax, nyqS, tab);
  main_kernel<<<(T_ / 16) * (B_ / BG), 512, 0, stream>>>(
      x, xmark, convw, pmax, nyqS, tab, out);
}

// Round 10
// 33.333 us; speedup vs baseline: 1.2997x; 1.2997x over previous
//
#include <hip/hip_runtime.h>
#include <math.h>

#define B_ 16
#define T_ 2048
#define N_ 8
#define D_ 512
#define DTW 4           // d-tiles (of 16) per wave

// -2*pi/2048
#define NEG_W0 (-3.0679615757712823e-3f)
// -2*pi/32
#define NEG_W32 (-0.19634954084936207f)
// -2*pi/1024
#define NEG_W1024 (-6.1359231515425647e-3f)
// -2*ln(10000)/512
#define NEG_LDIV (-0.035977892078031555f)

typedef __attribute__((ext_vector_type(8))) short bf16x8;
typedef __attribute__((ext_vector_type(4))) float f32x4;

// fp32 -> bf16 (round-to-nearest-even)
static __device__ __forceinline__ short f2bf(float f) {
  unsigned int u = __float_as_uint(f);
  unsigned int r = u + 0x7FFFu + ((u >> 16) & 1u);
  return (short)(r >> 16);
}

// ws layout (byte offsets): [0,4096) pmax[256]+nyqS[128];
// [4K, 4K+4M) FET tab f32[2048][512]; then amat bf16[512][32] (32 KB);
// xbf bf16[16][2048][8] (512 KB); cnt bf16[16][2048][8] (512 KB).
// Total ~5.3 MB; harness ws proven >= 193 MB (R6 use_alt ran).
// Everything is rewritten unconditionally every call.

// ---- launch 1 (545 blocks x 1024 thr, all independent):
//  blk <256: folded radix-32 FFT per (bn,parity) -> pmax/nyqS (unchanged)
//  256..511: FET tabgen  FET[t][2i]=sin(t*div_i), [2i+1]=cos
//  512..543: xbf + cnt row builders (one (b,t) row per thread)
//  544     : amat builder (thread d: conv slots 0..23, temporal 24..30, 31=0)
__global__ __launch_bounds__(1024) void prep_kernel(
    const float* __restrict__ x, const int* __restrict__ xmark,
    const float* __restrict__ convw, float* __restrict__ pmax,
    float* __restrict__ nyqS, float* __restrict__ tab,
    short* __restrict__ amat, short* __restrict__ xbf,
    short* __restrict__ cnt) {
  int tid = threadIdx.x;
  int blk = blockIdx.x;

  if (blk >= 256) {
    int j = blk - 256;
    if (j < 256) {                        // ---- FET tabgen ----
      int idx = j * 1024 + tid;           // one float4 per thread
      int t = idx >> 7;
      int d4 = idx & 127;
      float ft = (float)t;
      float dv0 = expf((float)(d4 * 2) * NEG_LDIV);
      float dv1 = expf((float)(d4 * 2 + 1) * NEG_LDIV);
      f32x4 v;
      float s0, c0, s1, c1;
      sincosf(ft * dv0, &s0, &c0);
      sincosf(ft * dv1, &s1, &c1);
      v[0] = s0; v[1] = c0; v[2] = s1; v[3] = c1;
      *(f32x4*)(tab + (size_t)idx * 4) = v;
    } else if (j < 288) {                 // ---- xbf + cnt rows ----
      int r = (j - 256) * 1024 + tid;     // r = b*T + t, 0..32767
      const float4* xr = (const float4*)(x + (size_t)r * 8);
      float4 lo = xr[0], hi = xr[1];
      bf16x8 v;
      v[0] = f2bf(lo.x); v[1] = f2bf(lo.y); v[2] = f2bf(lo.z); v[3] = f2bf(lo.w);
      v[4] = f2bf(hi.x); v[5] = f2bf(hi.y); v[6] = f2bf(hi.z); v[7] = f2bf(hi.w);
      *(bf16x8*)(xbf + (size_t)r * 8) = v;
      int4 mk = *(const int4*)(xmark + (size_t)r * 4);
      bf16x8 cv;
#pragma unroll
      for (int p = 0; p < 8; ++p) {
        int cc = (mk.x == p) + (mk.y == p) + (mk.z == p) + (mk.w == p);
        cv[p] = f2bf((float)cc);
      }
      *(bf16x8*)(cnt + (size_t)r * 8) = cv;
    } else {                              // ---- amat builder ----
      if (tid < 512) {
        int d = tid;
        short row[32];
#pragma unroll
        for (int kk = 0; kk < 24; ++kk) {
          int g = kk >> 3, n = kk & 7;    // A[d][g*8+n] = W[d][n][k=g]
          row[kk] = f2bf(convw[d * 24 + n * 3 + g]);
        }
        float divv = expf((float)(d >> 1) * NEG_LDIV);
        float s1, c1;
        sincosf(divv, &s1, &c1);
        int odd = d & 1;
        row[24] = f2bf(odd ? 1.f : 0.f);
        float ps = s1, pc = c1;
        row[25] = f2bf(odd ? pc : ps);
#pragma unroll
        for (int p = 2; p < 7; ++p) {
          float ns = fmaf(ps, c1, pc * s1);
          float nc = fmaf(pc, c1, -ps * s1);
          ps = ns; pc = nc;
          row[24 + p] = f2bf(odd ? pc : ps);
        }
        row[31] = 0;                      // marks < 7
#pragma unroll
        for (int q = 0; q < 4; ++q)
          *(bf16x8*)(amat + d * 32 + q * 8) = *(bf16x8*)&row[q * 8];
      }
    }
    return;
  }

  // ---- folded radix-32 FFT (unchanged from R9) ----
  __shared__ __align__(16) float2 ybuf[1024];
  __shared__ __align__(16) float2 Bl[1024];
  __shared__ __align__(16) float2 part[1024];
  __shared__ float swav[16];
  __shared__ float pwav[8];
  int bn = blk >> 1, parity = blk & 1;
  int b = bn >> 3, n = bn & 7;
  const float* xb = x + (size_t)b * (T_ * N_) + n;

  float va = xb[tid * 8];
  float vb = xb[(tid + 1024) * 8];
  float ea = va + vb;
  float sgn = (tid & 1) ? -ea : ea;       // Nyquist partial (-1)^t e_t
#pragma unroll
  for (int off = 32; off > 0; off >>= 1) sgn += __shfl_down(sgn, off);
  if ((tid & 63) == 0) swav[tid >> 6] = sgn;

  if (parity == 0) {
    ((float*)ybuf)[tid] = ea;
  } else {
    float o = va - vb;
    float c0, s0;
    sincosf((float)tid * NEG_W0, &s0, &c0);
    ybuf[tid] = make_float2(o * c0, o * s0);
  }
  __syncthreads();

  int m0 = tid & 31, t0 = tid >> 5;
  float d1 = (float)m0 * NEG_W32;
  float K1 = 2.0f * cosf(d1);
  float c = 1.f, s = 0.f, cp, sp;
  sincosf(-d1, &sp, &cp);
  float ar = 0.f, ai = 0.f;
  if (parity == 0) {
    const float* ya = (const float*)ybuf;
#pragma unroll 8
    for (int t1 = 0; t1 < 32; ++t1) {
      float y = ya[t1 * 32 + t0];
      ar = fmaf(y, c, ar); ai = fmaf(y, s, ai);
      float nc = fmaf(K1, c, -cp), ns = fmaf(K1, s, -sp);
      cp = c; sp = s; c = nc; s = ns;
    }
  } else {
#pragma unroll 8
    for (int t1 = 0; t1 < 32; ++t1) {
      float2 y = ybuf[t1 * 32 + t0];
      ar = fmaf(y.x, c, fmaf(-y.y, s, ar));
      ai = fmaf(y.x, s, fmaf(y.y, c, ai));
      float nc = fmaf(K1, c, -cp), ns = fmaf(K1, s, -sp);
      cp = c; sp = s; c = nc; s = ns;
    }
  }
  {
    float ct, st;
    sincosf((float)(t0 * m0) * NEG_W1024, &st, &ct);
    Bl[t0 * 32 + m0] = make_float2(ar * ct - ai * st, fmaf(ar, st, ai * ct));
  }
  __syncthreads();

  int m02 = tid & 31;
  int m1 = (tid >> 5) & 15;
  int h = tid >> 9;
  float d2 = (float)m1 * NEG_W32;
  float K2 = 2.0f * cosf(d2);
  int t0s = h * 16;
  float c2, s2, c2p, s2p;
  sincosf((float)t0s * d2, &s2, &c2);
  sincosf((float)(t0s - 1) * d2, &s2p, &c2p);
  float yr = 0.f, yi = 0.f;
#pragma unroll 8
  for (int j = 0; j < 16; ++j) {
    float2 bv = Bl[(t0s + j) * 32 + m02];
    yr = fmaf(bv.x, c2, fmaf(-bv.y, s2, yr));
    yi = fmaf(bv.x, s2, fmaf(bv.y, c2, yi));
    float nc = fmaf(K2, c2, -c2p), ns = fmaf(K2, s2, -s2p);
    c2p = c2; s2p = s2; c2 = nc; s2 = ns;
  }
  part[tid] = make_float2(yr, yi);
  __syncthreads();
  if (tid < 512) {
    float2 pa = part[tid], pb = part[tid + 512];
    float rr = pa.x + pb.x, ii = pa.y + pb.y;
    float P = fmaf(rr, rr, ii * ii);
#pragma unroll
    for (int off = 32; off > 0; off >>= 1) P = fmaxf(P, __shfl_down(P, off));
    if ((tid & 63) == 0) pwav[tid >> 6] = P;
  }
  __syncthreads();
  if (tid < 64) {
    float mxv = (tid < 8) ? pwav[tid] : 0.f;
    float svv = (tid < 16) ? swav[tid] : 0.f;
#pragma unroll
    for (int off = 8; off > 0; off >>= 1) {
      mxv = fmaxf(mxv, __shfl_down(mxv, off));
      svv += __shfl_down(svv, off);
    }
    if (tid == 0) {
      pmax[blk] = mxv;                    // unconditional plain store
      if (parity == 0) nyqS[bn] = svv;
    }
  }
}

// ---- main: pure streamer. Per thread: 4 afrag + 4 fet + 1 bfrag loads,
// 4 MFMA (slots 0..23 conv, 24..31 temporal), 8-FMA cyc epilogue, 4 stores.
// C^T layout (HW-verified, R8/R9 passed): lane c = t-col, 4 accs = 4
// consecutive d. Grid 2048: blk&127 = t-tile (16 rows), blk>>7 = batch.
__global__ __launch_bounds__(512, 6) void main_kernel(
    const short* __restrict__ amat, const short* __restrict__ xbf,
    const short* __restrict__ cnt, const float* __restrict__ tab,
    const float* __restrict__ pmax, const float* __restrict__ nyqS,
    float* __restrict__ out) {
  int tid = threadIdx.x;
  int lane = tid & 63;
  int w = tid >> 6;            // wave -> d in [w*64, w*64+64)
  int c = lane & 15;           // t-col / A d-row
  int g = lane >> 4;           // k-slot group / C d-subgroup
  int blk = blockIdx.x;
  int b = blk >> 7;
  int t0 = (blk & 127) * 16;

  // w1/w0 from Nyquist-argmax decision (24 L2-hot broadcast loads)
  int m = 0;
#pragma unroll
  for (int nn = 0; nn < 8; ++nn) {
    int bn = b * 8 + nn;
    float mx = fmaxf(pmax[2 * bn], pmax[2 * bn + 1]);
    float S = nyqS[bn];
    if (S * S > mx) ++m;
  }
  float w1 = (float)(8 - m) * 0.125f;
  float w0 = (float)m * 0.125f;

  bf16x8 afrag[DTW];
  f32x4 fet[DTW];
#pragma unroll
  for (int q = 0; q < DTW; ++q) {
    int d0 = (w * DTW + q) * 16;
    afrag[q] = *(const bf16x8*)(amat + (size_t)(d0 + c) * 32 + g * 8);
    fet[q] = *(const f32x4*)(tab + (size_t)(t0 + c) * D_ + d0 + g * 4);
  }

  bf16x8 bfrag;
  if (g < 3) {
    int row = (t0 + c + g - 1) & (T_ - 1);      // circular pad
    bfrag = *(const bf16x8*)(xbf + ((size_t)b * T_ + row) * 8);
  } else {
    bfrag = *(const bf16x8*)(cnt + ((size_t)b * T_ + t0 + c) * 8);
  }

  const f32x4 zac = {0.f, 0.f, 0.f, 0.f};
#pragma unroll
  for (int q = 0; q < DTW; ++q) {
    f32x4 acc = __builtin_amdgcn_mfma_f32_16x16x32_bf16(
        afrag[q], bfrag, zac, 0, 0, 0);
    f32x4 ov;
    ov[0] = fmaf(w1, fet[q][0], acc[0]);
    ov[1] = fmaf(w1, fet[q][1], acc[1]) + w0;
    ov[2] = fmaf(w1, fet[q][2], acc[2]);
    ov[3] = fmaf(w1, fet[q][3], acc[3]) + w0;
    int d0 = (w * DTW + q) * 16;
    *(f32x4*)(out + ((size_t)b * T_ + t0 + c) * D_ + d0 + g * 4) = ov;
  }
}

extern "C" void kernel_launch(void* const* d_in, const int* in_sizes, int n_in,
                              void* d_out, int out_size, void* d_ws, size_t ws_size,
                              hipStream_t stream) {
  const float* x = (const float*)d_in[0];
  const int* xmark = (const int*)d_in[1];
  const float* convw = (const float*)d_in[2];
  float* out = (float*)d_out;

  char* ws = (char*)d_ws;
  float* pmax = (float*)ws;                            // 256 f
  float* nyqS = pmax + 256;                            // 128 f
  float* tab = (float*)(ws + 4096);                    // 4 MB FET
  short* amat = (short*)(ws + 4096 + 4194304);         // 32 KB
  short* xbf = (short*)(ws + 4096 + 4194304 + 32768);  // 512 KB
  short* cnt = (short*)(ws + 4096 + 4194304 + 32768 + 524288);  // 512 KB

  prep_kernel<<<545, 1024, 0, stream>>>(x, xmark, convw, pmax, nyqS, tab,
                                        amat, xbf, cnt);
  main_kernel<<<B_ * (T_ / 16), 512, 0, stream>>>(amat, xbf, cnt, tab,
                                                  pmax, nyqS, out);
}

// Round 11
// 28.996 us; speedup vs baseline: 1.4941x; 1.1496x over previous
//
#include <hip/hip_runtime.h>
#include <math.h>

#define B_ 16
#define T_ 2048
#define N_ 8
#define D_ 512
#define DTW 4           // d-tiles (of 16) per wave
#define LPAD 520        // LDS row pitch (words): 512 + 8

// -2*pi/2048
#define NEG_W0 (-3.0679615757712823e-3f)
// -2*pi/32
#define NEG_W32 (-0.19634954084936207f)
// -2*pi/1024
#define NEG_W1024 (-6.1359231515425647e-3f)
// -2*ln(10000)/512
#define NEG_LDIV (-0.035977892078031555f)

typedef __attribute__((ext_vector_type(8))) short bf16x8;
typedef __attribute__((ext_vector_type(4))) float f32x4;

// fp32 -> bf16 (round-to-nearest-even)
static __device__ __forceinline__ short f2bf(float f) {
  unsigned int u = __float_as_uint(f);
  unsigned int r = u + 0x7FFFu + ((u >> 16) & 1u);
  return (short)(r >> 16);
}

// ws layout (byte offsets): [0,4096) pmax[256]+nyqS[128];
// [4K,4K+4M) FET tab f32[2048][512]; amat bf16[512][32] (32 KB);
// xbf bf16[16][2048][8] (512 KB); cnt bf16[16][2048][8] (512 KB).
// All rewritten unconditionally every call (no init/protocol hazards).

// ---- prep: 417 blocks x 1024 thr == one dispatch round (<= 512-block cap).
//  blk 0..255 : folded radix-32 FFT per (bn,parity) -> pmax/nyqS
//  blk 256..287: xbf (x cast to bf16 rows) + cnt (mark-count bf16x8 rows)
//  blk 288    : amat (A-matrix: conv slots 0..23, temporal 24..30, 31=0)
//  blk 289..416: FET tabgen, 2 float4 per thread
__global__ __launch_bounds__(1024) void prep_kernel(
    const float* __restrict__ x, const int* __restrict__ xmark,
    const float* __restrict__ convw, float* __restrict__ pmax,
    float* __restrict__ nyqS, float* __restrict__ tab,
    short* __restrict__ amat, short* __restrict__ xbf,
    short* __restrict__ cnt) {
  int tid = threadIdx.x;
  int blk = blockIdx.x;

  if (blk >= 256) {
    int j = blk - 256;
    if (j < 32) {                         // ---- xbf + cnt rows ----
      int r = j * 1024 + tid;             // r = b*T + t, 0..32767
      const float4* xr = (const float4*)(x + (size_t)r * 8);
      float4 lo = xr[0], hi = xr[1];
      bf16x8 v;
      v[0] = f2bf(lo.x); v[1] = f2bf(lo.y); v[2] = f2bf(lo.z); v[3] = f2bf(lo.w);
      v[4] = f2bf(hi.x); v[5] = f2bf(hi.y); v[6] = f2bf(hi.z); v[7] = f2bf(hi.w);
      *(bf16x8*)(xbf + (size_t)r * 8) = v;
      int4 mk = *(const int4*)(xmark + (size_t)r * 4);
      bf16x8 cv;
#pragma unroll
      for (int p = 0; p < 8; ++p) {
        int cc = (mk.x == p) + (mk.y == p) + (mk.z == p) + (mk.w == p);
        cv[p] = f2bf((float)cc);
      }
      *(bf16x8*)(cnt + (size_t)r * 8) = cv;
    } else if (j == 32) {                 // ---- amat builder ----
      if (tid < 512) {
        int d = tid;
        short row[32];
#pragma unroll
        for (int kk = 0; kk < 24; ++kk) {
          int g = kk >> 3, n = kk & 7;    // A[d][g*8+n] = W[d][n][k=g]
          row[kk] = f2bf(convw[d * 24 + n * 3 + g]);
        }
        float divv = expf((float)(d >> 1) * NEG_LDIV);
        float s1, c1;
        sincosf(divv, &s1, &c1);
        int odd = d & 1;
        row[24] = f2bf(odd ? 1.f : 0.f);
        float ps = s1, pc = c1;
        row[25] = f2bf(odd ? pc : ps);
#pragma unroll
        for (int p = 2; p < 7; ++p) {
          float ns = fmaf(ps, c1, pc * s1);
          float nc = fmaf(pc, c1, -ps * s1);
          ps = ns; pc = nc;
          row[24 + p] = f2bf(odd ? pc : ps);
        }
        row[31] = 0;                      // marks < 7
#pragma unroll
        for (int q = 0; q < 4; ++q)
          *(bf16x8*)(amat + d * 32 + q * 8) = *(bf16x8*)&row[q * 8];
      }
    } else {                              // ---- FET tabgen (2 f4/thread) ----
      int base = (j - 33) * 2048 + tid * 2;
#pragma unroll
      for (int u = 0; u < 2; ++u) {
        int idx = base + u;
        int t = idx >> 7;
        int d4 = idx & 127;
        float ft = (float)t;
        float dv0 = expf((float)(d4 * 2) * NEG_LDIV);
        float dv1 = expf((float)(d4 * 2 + 1) * NEG_LDIV);
        f32x4 v;
        float s0, c0, s1, c1;
        sincosf(ft * dv0, &s0, &c0);
        sincosf(ft * dv1, &s1, &c1);
        v[0] = s0; v[1] = c0; v[2] = s1; v[3] = c1;
        *(f32x4*)(tab + (size_t)idx * 4) = v;
      }
    }
    return;
  }

  // ---- folded radix-32 FFT (unchanged, validated R4..R10) ----
  __shared__ __align__(16) float2 ybuf[1024];
  __shared__ __align__(16) float2 Bl[1024];
  __shared__ __align__(16) float2 part[1024];
  __shared__ float swav[16];
  __shared__ float pwav[8];
  int bn = blk >> 1, parity = blk & 1;
  int b = bn >> 3, n = bn & 7;
  const float* xb = x + (size_t)b * (T_ * N_) + n;

  float va = xb[tid * 8];
  float vb = xb[(tid + 1024) * 8];
  float ea = va + vb;
  float sgn = (tid & 1) ? -ea : ea;       // Nyquist partial (-1)^t e_t
#pragma unroll
  for (int off = 32; off > 0; off >>= 1) sgn += __shfl_down(sgn, off);
  if ((tid & 63) == 0) swav[tid >> 6] = sgn;

  if (parity == 0) {
    ((float*)ybuf)[tid] = ea;
  } else {
    float o = va - vb;
    float c0, s0;
    sincosf((float)tid * NEG_W0, &s0, &c0);
    ybuf[tid] = make_float2(o * c0, o * s0);
  }
  __syncthreads();

  int m0 = tid & 31, t0 = tid >> 5;
  float d1 = (float)m0 * NEG_W32;
  float K1 = 2.0f * cosf(d1);
  float c = 1.f, s = 0.f, cp, sp;
  sincosf(-d1, &sp, &cp);
  float ar = 0.f, ai = 0.f;
  if (parity == 0) {
    const float* ya = (const float*)ybuf;
#pragma unroll 8
    for (int t1 = 0; t1 < 32; ++t1) {
      float y = ya[t1 * 32 + t0];
      ar = fmaf(y, c, ar); ai = fmaf(y, s, ai);
      float nc = fmaf(K1, c, -cp), ns = fmaf(K1, s, -sp);
      cp = c; sp = s; c = nc; s = ns;
    }
  } else {
#pragma unroll 8
    for (int t1 = 0; t1 < 32; ++t1) {
      float2 y = ybuf[t1 * 32 + t0];
      ar = fmaf(y.x, c, fmaf(-y.y, s, ar));
      ai = fmaf(y.x, s, fmaf(y.y, c, ai));
      float nc = fmaf(K1, c, -cp), ns = fmaf(K1, s, -sp);
      cp = c; sp = s; c = nc; s = ns;
    }
  }
  {
    float ct, st;
    sincosf((float)(t0 * m0) * NEG_W1024, &st, &ct);
    Bl[t0 * 32 + m0] = make_float2(ar * ct - ai * st, fmaf(ar, st, ai * ct));
  }
  __syncthreads();

  int m02 = tid & 31;
  int m1 = (tid >> 5) & 15;
  int h = tid >> 9;
  float d2 = (float)m1 * NEG_W32;
  float K2 = 2.0f * cosf(d2);
  int t0s = h * 16;
  float c2, s2, c2p, s2p;
  sincosf((float)t0s * d2, &s2, &c2);
  sincosf((float)(t0s - 1) * d2, &s2p, &c2p);
  float yr = 0.f, yi = 0.f;
#pragma unroll 8
  for (int j = 0; j < 16; ++j) {
    float2 bv = Bl[(t0s + j) * 32 + m02];
    yr = fmaf(bv.x, c2, fmaf(-bv.y, s2, yr));
    yi = fmaf(bv.x, s2, fmaf(bv.y, c2, yi));
    float nc = fmaf(K2, c2, -c2p), ns = fmaf(K2, s2, -s2p);
    c2p = c2; s2p = s2; c2 = nc; s2 = ns;
  }
  part[tid] = make_float2(yr, yi);
  __syncthreads();
  if (tid < 512) {
    float2 pa = part[tid], pb = part[tid + 512];
    float rr = pa.x + pb.x, ii = pa.y + pb.y;
    float P = fmaf(rr, rr, ii * ii);
#pragma unroll
    for (int off = 32; off > 0; off >>= 1) P = fmaxf(P, __shfl_down(P, off));
    if ((tid & 63) == 0) pwav[tid >> 6] = P;
  }
  __syncthreads();
  if (tid < 64) {
    float mxv = (tid < 8) ? pwav[tid] : 0.f;
    float svv = (tid < 16) ? swav[tid] : 0.f;
#pragma unroll
    for (int off = 8; off > 0; off >>= 1) {
      mxv = fmaxf(mxv, __shfl_down(mxv, off));
      svv += __shfl_down(svv, off);
    }
    if (tid == 0) {
      pmax[blk] = mxv;                    // unconditional plain store
      if (parity == 0) nyqS[bn] = svv;
    }
  }
}

// ---- main: MFMA (conv slots 0..23 + temporal 24..31) -> LDS repack ->
// fill-like sequential stores (4 x 8 KB contiguous rounds per batch-tile).
// Block = one 16-row t-tile x 512 d x 4 batches (128 KB stored / block).
// afrag/fet loaded once; grid 512 = 2 blocks/CU, all resident.
__global__ __launch_bounds__(512, 4) void main_kernel(
    const short* __restrict__ amat, const short* __restrict__ xbf,
    const short* __restrict__ cnt, const float* __restrict__ tab,
    const float* __restrict__ pmax, const float* __restrict__ nyqS,
    float* __restrict__ out) {
  __shared__ __align__(16) float lds[16 * LPAD];
  int tid = threadIdx.x;
  int lane = tid & 63;
  int w = tid >> 6;            // wave -> d in [w*64, w*64+64)
  int c = lane & 15;           // t-col / A d-row
  int g = lane >> 4;           // k-slot group / C d-subgroup
  int blk = blockIdx.x;
  int ttile = blk >> 2;
  int bg = blk & 3;            // batches bg*4 .. bg*4+3
  int t0 = ttile * 16;

  // w1/w0 for the 4 batches (wave-uniform scalar loads, L2-hot)
  float w1v[4], w0v[4];
#pragma unroll
  for (int j = 0; j < 4; ++j) {
    int b = bg * 4 + j;
    int m = 0;
#pragma unroll
    for (int nn = 0; nn < 8; ++nn) {
      int bn = b * 8 + nn;
      float mx = fmaxf(pmax[2 * bn], pmax[2 * bn + 1]);
      float S = nyqS[bn];
      if (S * S > mx) ++m;
    }
    w1v[j] = (float)(8 - m) * 0.125f;
    w0v[j] = (float)m * 0.125f;
  }

  bf16x8 afrag[DTW];
  f32x4 fet[DTW];
#pragma unroll
  for (int q = 0; q < DTW; ++q) {
    int d0 = (w * DTW + q) * 16;
    afrag[q] = *(const bf16x8*)(amat + (size_t)(d0 + c) * 32 + g * 8);
    fet[q] = *(const f32x4*)(tab + (size_t)(t0 + c) * D_ + d0 + g * 4);
  }

  const f32x4 zac = {0.f, 0.f, 0.f, 0.f};
#pragma unroll
  for (int j = 0; j < 4; ++j) {
    int b = bg * 4 + j;
    bf16x8 bfrag;
    if (g < 3) {
      int row = (t0 + c + g - 1) & (T_ - 1);    // circular pad
      bfrag = *(const bf16x8*)(xbf + ((size_t)b * T_ + row) * 8);
    } else {
      bfrag = *(const bf16x8*)(cnt + ((size_t)b * T_ + t0 + c) * 8);
    }
    float w1 = w1v[j], w0 = w0v[j];
#pragma unroll
    for (int q = 0; q < DTW; ++q) {
      f32x4 acc = __builtin_amdgcn_mfma_f32_16x16x32_bf16(
          afrag[q], bfrag, zac, 0, 0, 0);
      f32x4 ov;
      ov[0] = fmaf(w1, fet[q][0], acc[0]);
      ov[1] = fmaf(w1, fet[q][1], acc[1]) + w0;
      ov[2] = fmaf(w1, fet[q][2], acc[2]);
      ov[3] = fmaf(w1, fet[q][3], acc[3]) + w0;
      int d0 = (w * DTW + q) * 16;
      *(f32x4*)(lds + c * LPAD + d0 + g * 4) = ov;
    }
    __syncthreads();
    // stream the 16x512 tile out as 4 x 8KB perfectly sequential rounds
    float* obase = out + ((size_t)b * T_ + t0) * D_;
#pragma unroll
    for (int r = 0; r < 4; ++r) {
      int e = r * 2048 + tid * 4;               // element offset in tile
      int trow = e >> 9, col = e & 511;
      f32x4 v = *(const f32x4*)(lds + trow * LPAD + col);
      *(f32x4*)(obase + e) = v;
    }
    __syncthreads();                            // before next batch reuses lds
  }
}

extern "C" void kernel_launch(void* const* d_in, const int* in_sizes, int n_in,
                              void* d_out, int out_size, void* d_ws, size_t ws_size,
                              hipStream_t stream) {
  const float* x = (const float*)d_in[0];
  const int* xmark = (const int*)d_in[1];
  const float* convw = (const float*)d_in[2];
  float* out = (float*)d_out;

  char* ws = (char*)d_ws;
  float* pmax = (float*)ws;                            // 256 f
  float* nyqS = pmax + 256;                            // 128 f
  float* tab = (float*)(ws + 4096);                    // 4 MB FET
  short* amat = (short*)(ws + 4096 + 4194304);         // 32 KB
  short* xbf = (short*)(ws + 4096 + 4194304 + 32768);  // 512 KB
  short* cnt = (short*)(ws + 4096 + 4194304 + 32768 + 524288);  // 512 KB

  prep_kernel<<<417, 1024, 0, stream>>>(x, xmark, convw, pmax, nyqS, tab,
                                        amat, xbf, cnt);
  main_kernel<<<(T_ / 16) * (B_ / 4), 512, 0, stream>>>(amat, xbf, cnt, tab,
                                                        pmax, nyqS, out);
}